// Round 7
// baseline (601.114 us; speedup 1.0000x reference)
//
#include <hip/hip_runtime.h>
#include <math.h>

#define KDIM 1024
#define HID 256
#define NE 16
#define ROWS_BLK 128
#define KCH 32
#define NCHUNK 32
#define CH_BYTES 32768            // B chunk image: 2p*4kg*256col*16B
#define W2T_PLANE (NE * HID)
#define AB_STRIDE 16384           // A dbuf: 2 x 16KB @0
#define BBASE 32768               // B dbuf: 2 x 32KB @32768
#define BB_STRIDE 32768
#define SMEM_BYTES 98304

typedef __attribute__((ext_vector_type(8))) _Float16 f16x8;
typedef __attribute__((ext_vector_type(16))) float f32x16;
typedef __attribute__((ext_vector_type(4))) float f32x4;

__device__ __forceinline__ void gld16(const void* g, void* s) {
  __builtin_amdgcn_global_load_lds(
      (const __attribute__((address_space(1))) void*)g,
      (__attribute__((address_space(3))) void*)s, 16, 0, 0);
}

// R3/R6-proven planes: p1 = fl16(v), p2 = fl16((v - p1)*4096).
// Image layout: [c][p][kg][col] 16B granules.
__global__ void prep_w1(const float* __restrict__ W1, _Float16* __restrict__ img) {
  int idx = blockIdx.x * 256 + threadIdx.x;   // 0..32767
  int col = idx & 255, kgl = idx >> 8;        // kgl 0..127
  int c = kgl >> 2, kg = kgl & 3, k8 = kgl * 8;
  f16x8 p1, p2;
#pragma unroll
  for (int i = 0; i < 8; ++i) {
    float v = W1[(size_t)(k8 + i) * HID + col];
    _Float16 a = (_Float16)v;
    _Float16 b = (_Float16)((v - (float)a) * 4096.0f);
    p1[i] = a; p2[i] = b;
  }
  size_t off = (size_t)c * 16384 + (size_t)kg * 2048 + (size_t)col * 8;  // shorts
  *(f16x8*)(img + off) = p1;
  *(f16x8*)(img + off + 8192) = p2;
}

__global__ void prep_w2(const float* __restrict__ W2, _Float16* __restrict__ w2t) {
  int idx = blockIdx.x * 256 + threadIdx.x;   // 0..4095
  int e = idx & 15, k = idx >> 4;
  float v = W2[(size_t)k * NE + e];
  _Float16 a = (_Float16)v;
  _Float16 b = (_Float16)((v - (float)a) * 4096.0f);
  w2t[(size_t)e * HID + k] = a;
  w2t[W2T_PLANE + (size_t)e * HID + k] = b;
}

__global__ __launch_bounds__(512, 2) void fused_router(
    const float* __restrict__ x, const _Float16* __restrict__ w1img,
    const _Float16* __restrict__ w2t, const float* __restrict__ bias1,
    const float* __restrict__ bias2, float* __restrict__ outA,
    float* __restrict__ outL)
{
  extern __shared__ char smem[];
  const int t = threadIdx.x, l = t & 63, w = t >> 6;
  const int rowg = w >> 2, colg = w & 3;     // 2 x 4 waves: 128 rows x 256 cols
  const int l31 = l & 31, hi = l >> 5;
  const int R0 = blockIdx.x * ROWS_BLK;
  const int arow0 = rowg * 64 + l31;         // + 32*rt
  const int bcol0 = colg * 64 + l31;         // + 32*ct

  // x loader: row xr = t>>2 (0..127), granule xq = t&3 (k = xq*8..+7)
  const int xr = t >> 2, xq = t & 3;
  const float* xbase = x + (size_t)(R0 + xr) * KDIM + xq * 8;

  // B stager: thread t copies image bytes t*16 + i*8192 (linear)
  const char* ibase = (const char*)w1img + t * 16;

  f32x16 acc0[2][2], accA[2][2];
#pragma unroll
  for (int rt = 0; rt < 2; ++rt)
#pragma unroll
    for (int ct = 0; ct < 2; ++ct)
#pragma unroll
      for (int j = 0; j < 16; ++j) { acc0[rt][ct][j] = 0.f; accA[rt][ct][j] = 0.f; }

  float xv[8];

#define XLOAD(C_) do {                                                        \
    *(float4*)(xv)     = *(const float4*)(xbase + (size_t)(C_) * KCH);       \
    *(float4*)(xv + 4) = *(const float4*)(xbase + (size_t)(C_) * KCH + 4);   \
  } while (0)

#define BSTAGE(C_, BS_) do {                                                  \
    const char* is_ = ibase + (size_t)(C_) * CH_BYTES;                        \
    char* bd_ = smem + BBASE + (BS_) * BB_STRIDE + t * 16;                    \
    gld16(is_,         bd_);                                                  \
    gld16(is_ + 8192,  bd_ + 8192);                                           \
    gld16(is_ + 16384, bd_ + 16384);                                          \
    gld16(is_ + 24576, bd_ + 24576);                                          \
  } while (0)

#define ASPLIT(BS_) do {                                                      \
    f16x8 pa_, pb_;                                                           \
    _Pragma("unroll") for (int j_ = 0; j_ < 8; ++j_) {                        \
      float v_ = xv[j_];                                                      \
      _Float16 a_ = (_Float16)v_;                                             \
      _Float16 b_ = (_Float16)((v_ - (float)a_) * 4096.0f);                   \
      pa_[j_] = a_; pb_[j_] = b_;                                             \
    }                                                                         \
    int ao_ = (BS_) * AB_STRIDE + xq * 2048 + xr * 16;                        \
    *(f16x8*)(smem + ao_) = pa_;                                              \
    *(f16x8*)(smem + ao_ + 8192) = pb_;                                       \
  } while (0)

#define COMPUTE(BS_) do {                                                     \
    _Pragma("unroll") for (int s_ = 0; s_ < 2; ++s_) {                        \
      const int gg_ = 2 * s_ + hi;                                            \
      f16x8 a1_[2], a2_[2];                                                   \
      _Pragma("unroll") for (int rt_ = 0; rt_ < 2; ++rt_) {                   \
        int ao_ = (BS_) * AB_STRIDE + gg_ * 2048 + (arow0 + 32 * rt_) * 16;   \
        a1_[rt_] = *(const f16x8*)(smem + ao_);                               \
        a2_[rt_] = *(const f16x8*)(smem + ao_ + 8192);                        \
      }                                                                       \
      _Pragma("unroll") for (int ct_ = 0; ct_ < 2; ++ct_) {                   \
        int bo_ = BBASE + (BS_) * BB_STRIDE + gg_ * 4096                      \
                  + (bcol0 + 32 * ct_) * 16;                                  \
        f16x8 b1_ = *(const f16x8*)(smem + bo_);                              \
        f16x8 b2_ = *(const f16x8*)(smem + bo_ + 16384);                      \
        _Pragma("unroll") for (int rt_ = 0; rt_ < 2; ++rt_) {                 \
          acc0[rt_][ct_] = __builtin_amdgcn_mfma_f32_32x32x16_f16(            \
              a1_[rt_], b1_, acc0[rt_][ct_], 0, 0, 0);                        \
          accA[rt_][ct_] = __builtin_amdgcn_mfma_f32_32x32x16_f16(            \
              a1_[rt_], b2_, accA[rt_][ct_], 0, 0, 0);                        \
          accA[rt_][ct_] = __builtin_amdgcn_mfma_f32_32x32x16_f16(            \
              a2_[rt_], b1_, accA[rt_][ct_], 0, 0, 0);                        \
        }                                                                     \
      }                                                                       \
    }                                                                         \
  } while (0)

  // prologue
  XLOAD(0);
  BSTAGE(0, 0);
  ASPLIT(0);
  XLOAD(1);
  __syncthreads();

  int bsel = 0;
#pragma unroll 1
  for (int c = 0; c < NCHUNK; ++c) {
    if (c + 1 < NCHUNK) {
      BSTAGE(c + 1, bsel ^ 1);
      ASPLIT(bsel ^ 1);
      if (c + 2 < NCHUNK) XLOAD(c + 2);
    }
    COMPUTE(bsel);
    __syncthreads();
    bsel ^= 1;
  }

  // ---- epilogue: two R6-identical 64-row passes ----
  const float c12 = 1.0f / 4096.0f;
  const int tok = l & 15, g2 = l >> 4;

#pragma unroll 1
  for (int p = 0; p < 2; ++p) {
    __syncthreads();
    if (rowg == p) {
#pragma unroll
      for (int ct = 0; ct < 2; ++ct) {
        int col = bcol0 + 32 * ct;
        float bc = bias1[col];
        int cg = col >> 3, cb = (col & 7) * 2;
#pragma unroll
        for (int rt = 0; rt < 2; ++rt) {
#pragma unroll
          for (int r = 0; r < 16; ++r) {
            int tloc = 32 * rt + (r & 3) + 8 * (r >> 2) + 4 * hi;   // 0..63
            float v = acc0[rt][ct][r] + c12 * accA[rt][ct][r] + bc;
            v = v > 0.f ? v : expm1f(v);
            _Float16 h1 = (_Float16)v;
            _Float16 h2 = (_Float16)((v - (float)h1) * 4096.0f);
            int off = tloc * 512 + ((cg ^ (tloc & 7)) << 4) + cb;
            *(_Float16*)(smem + off) = h1;
            *(_Float16*)(smem + 32768 + off) = h2;
          }
        }
      }
    }
    __syncthreads();
    if (w < 4) {
      int tloc = w * 16 + tok;               // 0..63
      f32x4 L0, LA;
#pragma unroll
      for (int j = 0; j < 4; ++j) { L0[j] = 0.f; LA[j] = 0.f; }
      const _Float16* w2a = w2t + (size_t)tok * HID;
      const _Float16* w2b = w2a + W2T_PLANE;
#pragma unroll
      for (int kt = 0; kt < 8; ++kt) {
        int gg = (kt * 4 + g2) ^ (tloc & 7);
        f16x8 hb1 = *(const f16x8*)(smem + tloc * 512 + (gg << 4));
        f16x8 hb2 = *(const f16x8*)(smem + 32768 + tloc * 512 + (gg << 4));
        f16x8 wa = *(const f16x8*)(w2a + kt * 32 + 8 * g2);
        f16x8 wb = *(const f16x8*)(w2b + kt * 32 + 8 * g2);
        L0 = __builtin_amdgcn_mfma_f32_16x16x32_f16(wa, hb1, L0, 0, 0, 0);
        LA = __builtin_amdgcn_mfma_f32_16x16x32_f16(wa, hb2, LA, 0, 0, 0);
        LA = __builtin_amdgcn_mfma_f32_16x16x32_f16(wb, hb1, LA, 0, 0, 0);
      }
      float4 b2v = *(const float4*)(bias2 + 4 * g2);
      float L[4];
      L[0] = L0[0] + c12 * LA[0] + b2v.x;
      L[1] = L0[1] + c12 * LA[1] + b2v.y;
      L[2] = L0[2] + c12 * LA[2] + b2v.z;
      L[3] = L0[3] + c12 * LA[3] + b2v.w;

      float o1[4], o2[4], o3[4];
#pragma unroll
      for (int j = 0; j < 4; ++j) o1[j] = __shfl_xor(L[j], 16);
#pragma unroll
      for (int j = 0; j < 4; ++j) o2[j] = __shfl_xor(L[j], 32);
#pragma unroll
      for (int j = 0; j < 4; ++j) o3[j] = __shfl_xor(o1[j], 32);

      float all16[16];
#pragma unroll
      for (int cq = 0; cq < 4; ++cq) {
        int xg = cq ^ g2;
#pragma unroll
        for (int j = 0; j < 4; ++j) {
          float v = L[j];
          v = (xg == 1) ? o1[j] : v;
          v = (xg == 2) ? o2[j] : v;
          v = (xg == 3) ? o3[j] : v;
          all16[cq * 4 + j] = v;
        }
      }

      int i1 = 0; float m1 = all16[0];
#pragma unroll
      for (int e = 1; e < 16; ++e) { if (all16[e] > m1) { m1 = all16[e]; i1 = e; } }
      int i2 = -1; float m2 = -INFINITY;
#pragma unroll
      for (int e = 0; e < 16; ++e) { if (e != i1 && all16[e] > m2) { m2 = all16[e]; i2 = e; } }
      float ex = expf(m2 - m1);
      float sden = 1.f + ex;
      float A1 = 1.f / sden;
      float A2 = ex / sden;

      int e0 = 4 * g2;
      float4 alv;
      alv.x = (e0 + 0 == i1) ? A1 : ((e0 + 0 == i2) ? A2 : 0.f);
      alv.y = (e0 + 1 == i1) ? A1 : ((e0 + 1 == i2) ? A2 : 0.f);
      alv.z = (e0 + 2 == i1) ? A1 : ((e0 + 2 == i2) ? A2 : 0.f);
      alv.w = (e0 + 3 == i1) ? A1 : ((e0 + 3 == i2) ? A2 : 0.f);

      size_t orow = (size_t)(R0 + p * 64 + tloc);
      float4 lgv; lgv.x = L[0]; lgv.y = L[1]; lgv.z = L[2]; lgv.w = L[3];
      *(float4*)(outL + orow * NE + e0) = lgv;
      *(float4*)(outA + orow * NE + e0) = alv;
    }
  }
#undef XLOAD
#undef BSTAGE
#undef ASPLIT
#undef COMPUTE
}

extern "C" void kernel_launch(void* const* d_in, const int* in_sizes, int n_in,
                              void* d_out, int out_size, void* d_ws, size_t ws_size,
                              hipStream_t stream) {
  const float* x  = (const float*)d_in[0];
  const float* W1 = (const float*)d_in[1];
  const float* b1 = (const float*)d_in[2];
  const float* W2 = (const float*)d_in[3];
  const float* b2 = (const float*)d_in[4];
  _Float16* w1img = (_Float16*)d_ws;
  _Float16* w2t = w1img + (size_t)NCHUNK * (CH_BYTES / 2);
  float* outA = (float*)d_out;
  const size_t n_tok = (size_t)in_sizes[0] / KDIM;
  float* outL = outA + n_tok * NE;

  prep_w1<<<dim3(128), dim3(256), 0, stream>>>(W1, w1img);
  prep_w2<<<dim3(16), dim3(256), 0, stream>>>(W2, w2t);

  hipFuncSetAttribute((const void*)fused_router,
                      hipFuncAttributeMaxDynamicSharedMemorySize, SMEM_BYTES);
  fused_router<<<dim3((unsigned)(n_tok / ROWS_BLK)), dim3(512), SMEM_BYTES, stream>>>(
      x, w1img, w2t, b1, b2, outA, outL);
}